// Round 1
// baseline (44.920 us; speedup 1.0000x reference)
//
#include <hip/hip_runtime.h>

// out[j] = input_offset[permute[t]] + (j - output_offset[t])  for j in table t's
// output segment. Pure streaming int32 write (~268 MB); offsets tiny.
//
// Strategy: each table's segment is a linear ramp  out[j] = base_t + j  with
// base_t = input_offset[permute[t]] - output_offset[t].  Assign SPLIT blocks
// per table (balance the 16K..48K length spread), vectorize with int4 stores.

constexpr int SPLIT = 8;      // blocks per table
constexpr int BLOCK = 256;    // threads per block (4 waves)

__global__ __launch_bounds__(BLOCK) void ramp_fill(
    const int* __restrict__ permute,
    const int* __restrict__ input_offset,
    const int* __restrict__ output_offset,
    int* __restrict__ out,
    int tables)
{
    const int bid = blockIdx.x;
    const int t = bid / SPLIT;
    const int s = bid % SPLIT;
    if (t >= tables) return;

    const int start = output_offset[t];
    const int end   = output_offset[t + 1];
    const int base  = input_offset[permute[t]] - start;   // out[j] = base + j

    const int len   = end - start;
    const int chunk = (len + SPLIT - 1) / SPLIT;
    const int myStart = start + s * chunk;
    const int myEnd   = min(end, myStart + chunk);
    if (myStart >= myEnd) return;

    const int tid = threadIdx.x;

    // Head: scalar until 16B-aligned element index (multiple of 4).
    int alignedStart = (myStart + 3) & ~3;
    if (alignedStart > myEnd) alignedStart = myEnd;
    if (tid < alignedStart - myStart) {
        const int j = myStart + tid;
        out[j] = base + j;
    }

    int alignedEnd = myEnd & ~3;
    if (alignedEnd < alignedStart) alignedEnd = alignedStart;

    // Main: int4 vector stores, block-stride.
    int4* __restrict__ out4 = reinterpret_cast<int4*>(out);
    for (int j = alignedStart + tid * 4; j < alignedEnd; j += BLOCK * 4) {
        int4 v;
        v.x = base + j;
        v.y = base + j + 1;
        v.z = base + j + 2;
        v.w = base + j + 3;
        out4[j >> 2] = v;
    }

    // Tail: <4 scalar elements.
    const int jt = alignedEnd + tid;
    if (jt < myEnd) out[jt] = base + jt;
}

extern "C" void kernel_launch(void* const* d_in, const int* in_sizes, int n_in,
                              void* d_out, int out_size, void* d_ws, size_t ws_size,
                              hipStream_t stream) {
    const int* permute       = (const int*)d_in[0];
    const int* input_offset  = (const int*)d_in[1];
    const int* output_offset = (const int*)d_in[2];
    // d_in[3] = output_size scalar (unused; harness supplies out_size)
    int* out = (int*)d_out;
    const int tables = in_sizes[0];

    const int grid = tables * SPLIT;
    hipLaunchKernelGGL(ramp_fill, dim3(grid), dim3(BLOCK), 0, stream,
                       permute, input_offset, output_offset, out, tables);
}